// Round 17
// baseline (144.285 us; speedup 1.0000x reference)
//
#include <hip/hip_runtime.h>
#include <stdint.h>

#define D_MODEL 1024
#define D_STATE 16
#define BB 4
#define TT 2048
#define MM (BB*TT)       /* 8192 rows */
#define NCH 64           /* time chunks */
#define CL (TT/NCH)      /* 32 steps per chunk */

typedef __attribute__((ext_vector_type(4))) float f32x4;
typedef __attribute__((ext_vector_type(8))) short short8;

__device__ __forceinline__ unsigned short f2bf(float f) {
  union { float f; uint32_t u; } v; v.f = f;
  uint32_t r = v.u + 0x7FFFu + ((v.u >> 16) & 1u);   // RNE
  return (unsigned short)(r >> 16);
}
__device__ __forceinline__ float bf2f(unsigned short u) {
  union { uint32_t i; float f; } v; v.i = ((uint32_t)u) << 16; return v.f;
}

__device__ __forceinline__ float softplusf(float v) {
  return v > 20.f ? v : log1pf(expf(v));
}

__device__ __forceinline__ f32x4 splat4(float s) {
  f32x4 r; r[0]=s; r[1]=s; r[2]=s; r[3]=s; return r;
}
__device__ __forceinline__ f32x4 exp2v4(f32x4 v) {
  f32x4 r;
  r[0]=__builtin_amdgcn_exp2f(v[0]);
  r[1]=__builtin_amdgcn_exp2f(v[1]);
  r[2]=__builtin_amdgcn_exp2f(v[2]);
  r[3]=__builtin_amdgcn_exp2f(v[3]);
  return r;
}

// ---- merged prep: c2 table + f32->bf16 of Wd, Wo, x (single launch) --------
#define N4_C ((D_MODEL*D_STATE)/4)       /* 4096  */
#define N4_W ((D_MODEL*D_MODEL)/4)       /* 262144 */
#define N4_X ((MM*D_MODEL)/4)            /* 2097152 */
__global__ __launch_bounds__(256) void cvt_all_kernel(
    const float* __restrict__ a_log, float* __restrict__ c2tab,
    const float* __restrict__ wd_in, unsigned short* __restrict__ wd_out,
    const float* __restrict__ wo_in, unsigned short* __restrict__ wo_out,
    const float* __restrict__ x_in,  unsigned short* __restrict__ x_out)
{
  const int total = N4_C + 2*N4_W + N4_X;
  int i = blockIdx.x * blockDim.x + threadIdx.x;
  const int stride = gridDim.x * blockDim.x;
  for (; i < total; i += stride) {
    if (i < N4_C) {
      float4 v = ((const float4*)a_log)[i];
      float4 o;
      o.x = -(softplusf(v.x) + 1e-4f) * 1.44269504088896f;
      o.y = -(softplusf(v.y) + 1e-4f) * 1.44269504088896f;
      o.z = -(softplusf(v.z) + 1e-4f) * 1.44269504088896f;
      o.w = -(softplusf(v.w) + 1e-4f) * 1.44269504088896f;
      ((float4*)c2tab)[i] = o;
    } else {
      const float4* src; ushort4* dst; int j = i - N4_C;
      if (j < N4_W)        { src = (const float4*)wd_in; dst = (ushort4*)wd_out; }
      else if (j < 2*N4_W) { src = (const float4*)wo_in; dst = (ushort4*)wo_out; j -= N4_W; }
      else                 { src = (const float4*)x_in;  dst = (ushort4*)x_out;  j -= 2*N4_W; }
      float4 v = src[j];
      ushort4 o;
      o.x = f2bf(v.x); o.y = f2bf(v.y); o.z = f2bf(v.z); o.w = f2bf(v.w);
      dst[j] = o;
    }
  }
}

__device__ __forceinline__ void glds16(const char* g, char* l) {
  __builtin_amdgcn_global_load_lds(
      (const __attribute__((address_space(1))) void*)g,
      (__attribute__((address_space(3))) void*)l, 16, 0, 0);
}

// ---------------- bf16 GEMM, B^T: C[m][n] = sum_k A[m][k]*B[n][k] -----------
// BLOCK-TLP variant (m97-style residency): tile 128x64, BK=32, 256thr/4 waves
// (2x2, wave out 64x32), dbuf LDS (8KB A + 4KB B) x2 = 24KB -> 6 blocks/CU by
// LDS; grid = 64x16 = 1024 blocks = 4/CU resident (vs R16's 2/CU). Four
// independent barrier domains per CU hide each other's sync/stage stalls
// (m114 mechanism; m102's per-CU efficiency tracks blocks/CU 1->4).
// 64B rows; involution g(row) = (row>>1)&3 (R15-verified conflicts = 0):
//   LDS[row][slot] = global[row][slot ^ g(row)], slot = 16B unit.
//   staging: 3 gloads/wave (A chunks w, w+4; B chunk w); lane l -> row
//     chunk*16 + (l>>2), LDS slot l&3 (linear), global slot (l&3)^((l>>3)&3);
//     each 4-lane quad covers one aligned 64B line -> coalescing intact.
//   read: slot kh ^ ((r16>>1)&3): per row-parity 2 lanes/slot = free.
// Schedule: stage(i+1) [3 gloads] -> vmcnt(3) -> barrier -> 6 ds_read ->
// setprio(1) 8 MFMA setprio(0) -> barrier.
__device__ __forceinline__ void stage_tile(
    const unsigned short* __restrict__ A, const unsigned short* __restrict__ Bm,
    char* Al, char* Bl, int bm, int bn, int k0, int K, int w, int lane)
{
  const int lrow = lane >> 2;                              // 0..15
  const int scol = ((lane & 3) ^ ((lane >> 3) & 3)) << 4;  // swizzled global col
  const char* ga0 = (const char*)A + ((size_t)(bm + w*16     + lrow)*K + k0)*2 + scol;
  const char* ga1 = (const char*)A + ((size_t)(bm + (w+4)*16 + lrow)*K + k0)*2 + scol;
  const char* gb  = (const char*)Bm + ((size_t)(bn + w*16    + lrow)*K + k0)*2 + scol;
  glds16(ga0, Al + w*1024);
  glds16(ga1, Al + (w+4)*1024);
  glds16(gb,  Bl + w*1024);
}

template<bool SOFTPLUS>   // SOFTPLUS -> softplus epilogue + bf16 output
__global__ __launch_bounds__(256, 4) void gemm_bt_kernel(
    const unsigned short* __restrict__ A,   // M x K bf16 (row-major)
    const unsigned short* __restrict__ Bm,  // N x K bf16 (row-major, i.e. B^T)
    const float* __restrict__ bias,         // N
    void* __restrict__ Cout,                // M x N (bf16 if SOFTPLUS else f32)
    int M, int N, int K)
{
  __shared__ __align__(16) char Al[2][8192];  // [buf][128 rows][64B]
  __shared__ __align__(16) char Bl[2][4096];  // [buf][ 64 rows][64B]
  const int tid  = threadIdx.x;
  const int lane = tid & 63;
  const int w    = tid >> 6;           // wave 0..3
  const int wr   = w >> 1, wc = w & 1; // 2x2 wave grid, 64x32 out each
  const int r16  = lane & 15, kh = lane >> 4;

  // T1: bijective XCD chunk swizzle (nwg = 1024, % 8 == 0); 128 consecutive
  // newids per XCD = 8 m-panels (2MB A) x all 16 n-tiles (2MB B) -> L2-fit.
  const int nwg   = gridDim.x;
  const int flat  = blockIdx.x;
  const int newid = (flat & 7) * (nwg >> 3) + (flat >> 3);
  const int bm    = (newid >> 4) * 128;
  const int bn    = (newid & 15) * 64;

  // swizzled read column (per-thread constant)
  const int cr = (kh ^ ((r16 >> 1) & 3)) << 4;

  f32x4 acc[4][2] = {};
  const int NT = K >> 5;    // 32

  stage_tile(A, Bm, Al[0], Bl[0], bm, bn, 0, K, w, lane);

  for (int i = 0; i < NT; ++i) {
    if (i + 1 < NT) {
      stage_tile(A, Bm, Al[(i+1)&1], Bl[(i+1)&1], bm, bn, (i+1)*32, K, w, lane);
      asm volatile("s_waitcnt vmcnt(3)" ::: "memory");  // stage i's 3 loads done
    } else {
      asm volatile("s_waitcnt vmcnt(0)" ::: "memory");
    }
    __builtin_amdgcn_s_barrier();   // stage i visible to all waves

    const char* Ab = Al[i & 1] + cr;
    const char* Bb = Bl[i & 1] + cr;
    short8 af[4], bf[2];
    #pragma unroll
    for (int m = 0; m < 4; ++m)
      af[m] = *(const short8*)(Ab + (wr*64 + m*16 + r16)*64);
    #pragma unroll
    for (int n = 0; n < 2; ++n)
      bf[n] = *(const short8*)(Bb + (wc*32 + n*16 + r16)*64);
    __builtin_amdgcn_s_setprio(1);
    #pragma unroll
    for (int m = 0; m < 4; ++m)
      #pragma unroll
      for (int n = 0; n < 2; ++n)
        acc[m][n] = __builtin_amdgcn_mfma_f32_16x16x32_bf16(af[m], bf[n], acc[m][n], 0, 0, 0);
    __builtin_amdgcn_s_setprio(0);
    __builtin_amdgcn_s_barrier();   // reads of buf[i&1] retired before overwrite
  }

  // epilogue: row = bm + wr*64 + m*16 + kh*4 + j ; col = bn + wc*32 + n*16 + r16
  #pragma unroll
  for (int n = 0; n < 2; ++n) {
    const int col = bn + wc*32 + n*16 + r16;
    const float bv = bias[col];
    #pragma unroll
    for (int m = 0; m < 4; ++m) {
      #pragma unroll
      for (int j = 0; j < 4; ++j) {
        const int row = bm + wr*64 + m*16 + kh*4 + j;
        float v = acc[m][n][j] + bv;
        if (SOFTPLUS) {
          v = softplusf(v);
          ((unsigned short*)Cout)[(size_t)row*N + col] = f2bf(v);
        } else {
          ((float*)Cout)[(size_t)row*N + col] = v;
        }
      }
    }
  }
}

// ---------------- scan pass 1: per-chunk local state L and sum(dt) ----------
__global__ __launch_bounds__(256) void scan_pass1_kernel(
    const unsigned short* __restrict__ x, const unsigned short* __restrict__ delta,
    const float* __restrict__ c2tab,
    float* __restrict__ Lc, float* __restrict__ dts_out)
{
  const int e  = blockIdx.x * 256 + threadIdx.x;
  const int b  = blockIdx.y >> 6;            // NCH = 64
  const int c  = blockIdx.y & (NCH-1);

  const f32x4* c2p = (const f32x4*)(c2tab + (size_t)e*D_STATE);
  const f32x4 c20=c2p[0], c21=c2p[1], c22=c2p[2], c23=c2p[3];

  f32x4 S0=splat4(0.f), S1=splat4(0.f), S2=splat4(0.f), S3=splat4(0.f);
  const size_t base = ((size_t)b*TT + (size_t)c*CL)*D_MODEL + e;
  const unsigned short* xp = x + base;
  const unsigned short* dp = delta + base;
  float dts = 0.f;
  #pragma unroll 4
  for (int t = 0; t < CL; ++t) {
    const float dt = bf2f(dp[(size_t)t*D_MODEL]);
    const float xv = bf2f(xp[(size_t)t*D_MODEL]);
    dts += dt;
    const f32x4 u4 = splat4(dt*xv);
    const f32x4 d4 = splat4(dt);
    S0 = exp2v4(c20*d4)*S0 + u4;
    S1 = exp2v4(c21*d4)*S1 + u4;
    S2 = exp2v4(c22*d4)*S2 + u4;
    S3 = exp2v4(c23*d4)*S3 + u4;
  }
  const size_t ci = ((size_t)c*BB + b)*D_MODEL + e;
  dts_out[ci] = dts;
  f32x4* Lp = (f32x4*)&Lc[ci*D_STATE];
  Lp[0]=S0; Lp[1]=S1; Lp[2]=S2; Lp[3]=S3;
}

// ---------------- scan pass 2: in-place exclusive scan over chunks ----------
__global__ __launch_bounds__(256) void scan_pass2_kernel(
    const float* __restrict__ c2tab,
    float* __restrict__ Lc, const float* __restrict__ dts)
{
  const int tid = blockIdx.x * 256 + threadIdx.x;  // < 65536
  const int e = (tid >> 4) & (D_MODEL - 1);
  const int b = tid >> 14;
  const float c2 = c2tab[tid & (D_MODEL*D_STATE - 1)];  // e*16 + s
  float S = 0.f;
  for (int c = 0; c < NCH; ++c) {
    const size_t ce  = ((size_t)c*BB + b)*D_MODEL + e;
    const size_t idx = ce*D_STATE + (tid & 15);
    const float L  = Lc[idx];
    const float Ac = __builtin_amdgcn_exp2f(c2 * dts[ce]);
    Lc[idx] = S;                 // exclusive prefix (chunk initial state)
    S = Ac*S + L;
  }
}

// ---------------- scan pass 3: recompute with carry-in, emit y (bf16) -------
__global__ __launch_bounds__(256) void scan_pass3_kernel(
    const unsigned short* __restrict__ x, const unsigned short* __restrict__ delta,
    const float* __restrict__ c2tab, const float* __restrict__ b_param,
    const float* __restrict__ Lc, unsigned short* __restrict__ yb)
{
  const int e  = blockIdx.x * 256 + threadIdx.x;
  const int b  = blockIdx.y >> 6;
  const int c  = blockIdx.y & (NCH-1);

  const f32x4* c2p = (const f32x4*)(c2tab + (size_t)e*D_STATE);
  const f32x4 c20=c2p[0], c21=c2p[1], c22=c2p[2], c23=c2p[3];
  const f32x4* bpp = (const f32x4*)(b_param + (size_t)e*D_STATE);
  const f32x4 bp0=bpp[0], bp1=bpp[1], bp2=bpp[2], bp3=bpp[3];

  const size_t ci = ((size_t)c*BB + b)*D_MODEL + e;
  const f32x4* Lp = (const f32x4*)&Lc[ci*D_STATE];
  f32x4 S0=Lp[0], S1=Lp[1], S2=Lp[2], S3=Lp[3];

  const size_t base = ((size_t)b*TT + (size_t)c*CL)*D_MODEL + e;
  const unsigned short* xp = x + base;
  const unsigned short* dp = delta + base;
  #pragma unroll 4
  for (int t = 0; t < CL; ++t) {
    const float dt = bf2f(dp[(size_t)t*D_MODEL]);
    const float xv = bf2f(xp[(size_t)t*D_MODEL]);
    const f32x4 u4 = splat4(dt*xv);
    const f32x4 d4 = splat4(dt);
    S0 = exp2v4(c20*d4)*S0 + u4;
    S1 = exp2v4(c21*d4)*S1 + u4;
    S2 = exp2v4(c22*d4)*S2 + u4;
    S3 = exp2v4(c23*d4)*S3 + u4;
    const f32x4 yv = bp0*S0 + bp1*S1 + bp2*S2 + bp3*S3;
    const float y = (yv[0]+yv[1]) + (yv[2]+yv[3]);
    yb[base + (size_t)t*D_MODEL] = f2bf(y);
  }
}

// ---------------------------------------------------------------------------
extern "C" void kernel_launch(void* const* d_in, const int* in_sizes, int n_in,
                              void* d_out, int out_size, void* d_ws, size_t ws_size,
                              hipStream_t stream)
{
  (void)in_sizes; (void)n_in; (void)out_size; (void)ws_size;
  const float* x       = (const float*)d_in[0];
  const float* Wd      = (const float*)d_in[1];
  const float* bd      = (const float*)d_in[2];
  const float* a_log   = (const float*)d_in[3];
  const float* b_param = (const float*)d_in[4];
  const float* Wo      = (const float*)d_in[5];
  const float* bo      = (const float*)d_in[6];
  float* out = (float*)d_out;

  // workspace layout, 1MB units, no overlaps:
  //   xb[0,16M) wdb[16M,18M) wob[18M,20M) deltab[20M,36M) yb[36M,52M)
  //   Lc[52M,68M) dts[68M,69M)
  char* ws = (char*)d_ws;
  unsigned short* xb     = (unsigned short*)(ws);
  unsigned short* wdb    = (unsigned short*)(ws + 16777216);
  unsigned short* wob    = (unsigned short*)(ws + 18874368);
  unsigned short* deltab = (unsigned short*)(ws + 20971520);
  unsigned short* yb     = (unsigned short*)(ws + 37748736);
  float*          Lc     = (float*)(ws + 54525952);
  float*          dts    = (float*)(ws + 71303168);

  // c2 table (64 KB) at the head of d_out; consumed by scans, then GEMM2
  // overwrites all of d_out. Deterministic each call.
  float* c2tab = (float*)d_out;

  cvt_all_kernel<<<2048, 256, 0, stream>>>(
      a_log, c2tab, Wd, wdb, Wo, wob, x, xb);

  gemm_bt_kernel<true><<<dim3((MM/128)*(D_MODEL/64)), 256, 0, stream>>>(
      xb, wdb, bd, (void*)deltab, MM, D_MODEL, D_MODEL);

  scan_pass1_kernel<<<dim3(D_MODEL/256, BB*NCH), 256, 0, stream>>>(
      xb, deltab, c2tab, Lc, dts);
  scan_pass2_kernel<<<(BB*D_MODEL*D_STATE)/256, 256, 0, stream>>>(
      c2tab, Lc, dts);
  scan_pass3_kernel<<<dim3(D_MODEL/256, BB*NCH), 256, 0, stream>>>(
      xb, deltab, c2tab, b_param, Lc, yb);

  gemm_bt_kernel<false><<<dim3((MM/128)*(D_MODEL/64)), 256, 0, stream>>>(
      yb, wob, bo, (void*)out, MM, D_MODEL, D_MODEL);
}

// Round 18
// 139.559 us; speedup vs baseline: 1.0339x; 1.0339x over previous
//
#include <hip/hip_runtime.h>
#include <stdint.h>

#define D_MODEL 1024
#define D_STATE 16
#define BB 4
#define TT 2048
#define MM (BB*TT)       /* 8192 rows */
#define NCH 64           /* time chunks */
#define CL (TT/NCH)      /* 32 steps per chunk */

typedef __attribute__((ext_vector_type(4))) float f32x4;
typedef __attribute__((ext_vector_type(8))) short short8;

__device__ __forceinline__ unsigned short f2bf(float f) {
  union { float f; uint32_t u; } v; v.f = f;
  uint32_t r = v.u + 0x7FFFu + ((v.u >> 16) & 1u);   // RNE
  return (unsigned short)(r >> 16);
}
__device__ __forceinline__ float bf2f(unsigned short u) {
  union { uint32_t i; float f; } v; v.i = ((uint32_t)u) << 16; return v.f;
}

__device__ __forceinline__ float softplusf(float v) {
  return v > 20.f ? v : log1pf(expf(v));
}

__device__ __forceinline__ f32x4 splat4(float s) {
  f32x4 r; r[0]=s; r[1]=s; r[2]=s; r[3]=s; return r;
}
__device__ __forceinline__ f32x4 exp2v4(f32x4 v) {
  f32x4 r;
  r[0]=__builtin_amdgcn_exp2f(v[0]);
  r[1]=__builtin_amdgcn_exp2f(v[1]);
  r[2]=__builtin_amdgcn_exp2f(v[2]);
  r[3]=__builtin_amdgcn_exp2f(v[3]);
  return r;
}

// ---- merged prep: c2 table + f32->bf16 of Wd, Wo, x (single launch) --------
#define N4_C ((D_MODEL*D_STATE)/4)       /* 4096  */
#define N4_W ((D_MODEL*D_MODEL)/4)       /* 262144 */
#define N4_X ((MM*D_MODEL)/4)            /* 2097152 */
__global__ __launch_bounds__(256) void cvt_all_kernel(
    const float* __restrict__ a_log, float* __restrict__ c2tab,
    const float* __restrict__ wd_in, unsigned short* __restrict__ wd_out,
    const float* __restrict__ wo_in, unsigned short* __restrict__ wo_out,
    const float* __restrict__ x_in,  unsigned short* __restrict__ x_out)
{
  const int total = N4_C + 2*N4_W + N4_X;
  int i = blockIdx.x * blockDim.x + threadIdx.x;
  const int stride = gridDim.x * blockDim.x;
  for (; i < total; i += stride) {
    if (i < N4_C) {
      float4 v = ((const float4*)a_log)[i];
      float4 o;
      o.x = -(softplusf(v.x) + 1e-4f) * 1.44269504088896f;
      o.y = -(softplusf(v.y) + 1e-4f) * 1.44269504088896f;
      o.z = -(softplusf(v.z) + 1e-4f) * 1.44269504088896f;
      o.w = -(softplusf(v.w) + 1e-4f) * 1.44269504088896f;
      ((float4*)c2tab)[i] = o;
    } else {
      const float4* src; ushort4* dst; int j = i - N4_C;
      if (j < N4_W)        { src = (const float4*)wd_in; dst = (ushort4*)wd_out; }
      else if (j < 2*N4_W) { src = (const float4*)wo_in; dst = (ushort4*)wo_out; j -= N4_W; }
      else                 { src = (const float4*)x_in;  dst = (ushort4*)x_out;  j -= 2*N4_W; }
      float4 v = src[j];
      ushort4 o;
      o.x = f2bf(v.x); o.y = f2bf(v.y); o.z = f2bf(v.z); o.w = f2bf(v.w);
      dst[j] = o;
    }
  }
}

__device__ __forceinline__ void glds16(const char* g, char* l) {
  __builtin_amdgcn_global_load_lds(
      (const __attribute__((address_space(1))) void*)g,
      (__attribute__((address_space(3))) void*)l, 16, 0, 0);
}

// ---------------- bf16 GEMM, B^T: C[m][n] = sum_k A[m][k]*B[n][k] -----------
// DEEP-PREFETCH A/B on the 52us R16 base. 128x128 tile, K split into 32
// HALF-TILES of 32-k (64B rows). Ring of 4 half-slots per operand
// (4 x 8KB A + 4 x 8KB B = 64KB, 2 blocks/CU — same LDS as R16).
// Per half h: vmcnt(4) counted (tail 2/0) -> barrier -> issue stage(h+3)
// -> 6 ds_read -> setprio(1) 8 MFMA setprio(0).  Same barrier count (32),
// same contiguous 1KB/wave staging, same verified involution (conflicts=0):
//   LDS[row][slot16] = global[row][slot16 ^ ((row>>1)&3)]
//   staging: lane l -> row w*16+(l>>2), global slot (l&3)^((l>>3)&3);
//   read slot kh^((r16>>1)&3).  ONLY the prefetch distance changes: 1 -> 3.
// Race-safe: stage(h+3) targets slot (h-1)&3; its readers' ds_reads retired
// before their body-h barrier arrival (lgkmcnt precedes MFMA); issue is
// post-barrier, so all waves' reads are done.
template<bool SOFTPLUS>   // SOFTPLUS -> softplus epilogue + bf16 output
__global__ __launch_bounds__(512, 4) void gemm_bt_kernel(
    const unsigned short* __restrict__ A,   // M x K bf16 (row-major)
    const unsigned short* __restrict__ Bm,  // N x K bf16 (row-major, i.e. B^T)
    const float* __restrict__ bias,         // N
    void* __restrict__ Cout,                // M x N (bf16 if SOFTPLUS else f32)
    int M, int N, int K)
{
  __shared__ __align__(16) char As[4][8192];  // [slot][128 rows][64B]
  __shared__ __align__(16) char Bs[4][8192];
  const int tid  = threadIdx.x;
  const int lane = tid & 63;
  const int w    = tid >> 6;           // wave 0..7
  const int wr   = w >> 2, wc = w & 3; // 2x4 wave grid, 64x32 out each
  const int r16  = lane & 15, kh = lane >> 4;

  // T1: bijective XCD chunk swizzle (nwg = 512, % 8 == 0)
  const int nwg   = gridDim.x;
  const int flat  = blockIdx.x;
  const int newid = (flat & 7) * (nwg >> 3) + (flat >> 3);
  const int bm    = (newid >> 3) * 128;
  const int bn    = (newid & 7) * 128;

  // staging (per-lane constants): row w*16+(l>>2), swizzled global col
  const int lrow = lane >> 2;
  const int scol = ((lane & 3) ^ ((lane >> 3) & 3)) << 4;
  const char* ga = (const char*)A  + ((size_t)(bm + w*16 + lrow)*K)*2 + scol;
  const char* gb = (const char*)Bm + ((size_t)(bn + w*16 + lrow)*K)*2 + scol;
  const int ldst = w*1024;                       // wave-uniform LDS dest

  // swizzled read column (per-thread constant)
  const int cr = (kh ^ ((r16 >> 1) & 3)) << 4;

  f32x4 acc[4][2] = {};
  const int NH = (K >> 5);   // 32 half-tiles

  // prologue: stages 0,1,2 in flight (6 loads/wave)
  #pragma unroll
  for (int p = 0; p < 3; ++p) {
    glds16(ga + (size_t)p*64, As[p] + ldst);
    glds16(gb + (size_t)p*64, Bs[p] + ldst);
  }

  for (int h = 0; h < NH; ++h) {
    if (h + 2 < NH)      asm volatile("s_waitcnt vmcnt(4)" ::: "memory");
    else if (h + 1 < NH) asm volatile("s_waitcnt vmcnt(2)" ::: "memory");
    else                 asm volatile("s_waitcnt vmcnt(0)" ::: "memory");
    __builtin_amdgcn_s_barrier();   // half h staged; slot (h-1)&3 reads retired

    if (h + 3 < NH) {
      glds16(ga + (size_t)(h+3)*64, As[(h+3)&3] + ldst);
      glds16(gb + (size_t)(h+3)*64, Bs[(h+3)&3] + ldst);
    }

    const char* Ab = As[h & 3] + cr;
    const char* Bb = Bs[h & 3] + cr;
    short8 af[4], bf[2];
    #pragma unroll
    for (int m = 0; m < 4; ++m)
      af[m] = *(const short8*)(Ab + (wr*64 + m*16 + r16)*64);
    #pragma unroll
    for (int n = 0; n < 2; ++n)
      bf[n] = *(const short8*)(Bb + (wc*32 + n*16 + r16)*64);
    __builtin_amdgcn_s_setprio(1);
    #pragma unroll
    for (int m = 0; m < 4; ++m)
      #pragma unroll
      for (int n = 0; n < 2; ++n)
        acc[m][n] = __builtin_amdgcn_mfma_f32_16x16x32_bf16(af[m], bf[n], acc[m][n], 0, 0, 0);
    __builtin_amdgcn_s_setprio(0);
  }

  // epilogue: row = bm + wr*64 + m*16 + kh*4 + j ; col = bn + wc*32 + n*16 + r16
  #pragma unroll
  for (int n = 0; n < 2; ++n) {
    const int col = bn + wc*32 + n*16 + r16;
    const float bv = bias[col];
    #pragma unroll
    for (int m = 0; m < 4; ++m) {
      #pragma unroll
      for (int j = 0; j < 4; ++j) {
        const int row = bm + wr*64 + m*16 + kh*4 + j;
        float v = acc[m][n][j] + bv;
        if (SOFTPLUS) {
          v = softplusf(v);
          ((unsigned short*)Cout)[(size_t)row*N + col] = f2bf(v);
        } else {
          ((float*)Cout)[(size_t)row*N + col] = v;
        }
      }
    }
  }
}

// ---------------- scan pass 1: per-chunk local state L and sum(dt) ----------
__global__ __launch_bounds__(256) void scan_pass1_kernel(
    const unsigned short* __restrict__ x, const unsigned short* __restrict__ delta,
    const float* __restrict__ c2tab,
    float* __restrict__ Lc, float* __restrict__ dts_out)
{
  const int e  = blockIdx.x * 256 + threadIdx.x;
  const int b  = blockIdx.y >> 6;            // NCH = 64
  const int c  = blockIdx.y & (NCH-1);

  const f32x4* c2p = (const f32x4*)(c2tab + (size_t)e*D_STATE);
  const f32x4 c20=c2p[0], c21=c2p[1], c22=c2p[2], c23=c2p[3];

  f32x4 S0=splat4(0.f), S1=splat4(0.f), S2=splat4(0.f), S3=splat4(0.f);
  const size_t base = ((size_t)b*TT + (size_t)c*CL)*D_MODEL + e;
  const unsigned short* xp = x + base;
  const unsigned short* dp = delta + base;
  float dts = 0.f;
  #pragma unroll 4
  for (int t = 0; t < CL; ++t) {
    const float dt = bf2f(dp[(size_t)t*D_MODEL]);
    const float xv = bf2f(xp[(size_t)t*D_MODEL]);
    dts += dt;
    const f32x4 u4 = splat4(dt*xv);
    const f32x4 d4 = splat4(dt);
    S0 = exp2v4(c20*d4)*S0 + u4;
    S1 = exp2v4(c21*d4)*S1 + u4;
    S2 = exp2v4(c22*d4)*S2 + u4;
    S3 = exp2v4(c23*d4)*S3 + u4;
  }
  const size_t ci = ((size_t)c*BB + b)*D_MODEL + e;
  dts_out[ci] = dts;
  f32x4* Lp = (f32x4*)&Lc[ci*D_STATE];
  Lp[0]=S0; Lp[1]=S1; Lp[2]=S2; Lp[3]=S3;
}

// ---------------- scan pass 2: in-place exclusive scan over chunks ----------
__global__ __launch_bounds__(256) void scan_pass2_kernel(
    const float* __restrict__ c2tab,
    float* __restrict__ Lc, const float* __restrict__ dts)
{
  const int tid = blockIdx.x * 256 + threadIdx.x;  // < 65536
  const int e = (tid >> 4) & (D_MODEL - 1);
  const int b = tid >> 14;
  const float c2 = c2tab[tid & (D_MODEL*D_STATE - 1)];  // e*16 + s
  float S = 0.f;
  for (int c = 0; c < NCH; ++c) {
    const size_t ce  = ((size_t)c*BB + b)*D_MODEL + e;
    const size_t idx = ce*D_STATE + (tid & 15);
    const float L  = Lc[idx];
    const float Ac = __builtin_amdgcn_exp2f(c2 * dts[ce]);
    Lc[idx] = S;                 // exclusive prefix (chunk initial state)
    S = Ac*S + L;
  }
}

// ---------------- scan pass 3: recompute with carry-in, emit y (bf16) -------
__global__ __launch_bounds__(256) void scan_pass3_kernel(
    const unsigned short* __restrict__ x, const unsigned short* __restrict__ delta,
    const float* __restrict__ c2tab, const float* __restrict__ b_param,
    const float* __restrict__ Lc, unsigned short* __restrict__ yb)
{
  const int e  = blockIdx.x * 256 + threadIdx.x;
  const int b  = blockIdx.y >> 6;
  const int c  = blockIdx.y & (NCH-1);

  const f32x4* c2p = (const f32x4*)(c2tab + (size_t)e*D_STATE);
  const f32x4 c20=c2p[0], c21=c2p[1], c22=c2p[2], c23=c2p[3];
  const f32x4* bpp = (const f32x4*)(b_param + (size_t)e*D_STATE);
  const f32x4 bp0=bpp[0], bp1=bpp[1], bp2=bpp[2], bp3=bpp[3];

  const size_t ci = ((size_t)c*BB + b)*D_MODEL + e;
  const f32x4* Lp = (const f32x4*)&Lc[ci*D_STATE];
  f32x4 S0=Lp[0], S1=Lp[1], S2=Lp[2], S3=Lp[3];

  const size_t base = ((size_t)b*TT + (size_t)c*CL)*D_MODEL + e;
  const unsigned short* xp = x + base;
  const unsigned short* dp = delta + base;
  #pragma unroll 4
  for (int t = 0; t < CL; ++t) {
    const float dt = bf2f(dp[(size_t)t*D_MODEL]);
    const float xv = bf2f(xp[(size_t)t*D_MODEL]);
    const f32x4 u4 = splat4(dt*xv);
    const f32x4 d4 = splat4(dt);
    S0 = exp2v4(c20*d4)*S0 + u4;
    S1 = exp2v4(c21*d4)*S1 + u4;
    S2 = exp2v4(c22*d4)*S2 + u4;
    S3 = exp2v4(c23*d4)*S3 + u4;
    const f32x4 yv = bp0*S0 + bp1*S1 + bp2*S2 + bp3*S3;
    const float y = (yv[0]+yv[1]) + (yv[2]+yv[3]);
    yb[base + (size_t)t*D_MODEL] = f2bf(y);
  }
}

// ---------------------------------------------------------------------------
extern "C" void kernel_launch(void* const* d_in, const int* in_sizes, int n_in,
                              void* d_out, int out_size, void* d_ws, size_t ws_size,
                              hipStream_t stream)
{
  (void)in_sizes; (void)n_in; (void)out_size; (void)ws_size;
  const float* x       = (const float*)d_in[0];
  const float* Wd      = (const float*)d_in[1];
  const float* bd      = (const float*)d_in[2];
  const float* a_log   = (const float*)d_in[3];
  const float* b_param = (const float*)d_in[4];
  const float* Wo      = (const float*)d_in[5];
  const float* bo      = (const float*)d_in[6];
  float* out = (float*)d_out;

  // workspace layout, 1MB units, no overlaps:
  //   xb[0,16M) wdb[16M,18M) wob[18M,20M) deltab[20M,36M) yb[36M,52M)
  //   Lc[52M,68M) dts[68M,69M)
  char* ws = (char*)d_ws;
  unsigned short* xb     = (unsigned short*)(ws);
  unsigned short* wdb    = (unsigned short*)(ws + 16777216);
  unsigned short* wob    = (unsigned short*)(ws + 18874368);
  unsigned short* deltab = (unsigned short*)(ws + 20971520);
  unsigned short* yb     = (unsigned short*)(ws + 37748736);
  float*          Lc     = (float*)(ws + 54525952);
  float*          dts    = (float*)(ws + 71303168);

  // c2 table (64 KB) at the head of d_out; consumed by scans, then GEMM2
  // overwrites all of d_out. Deterministic each call.
  float* c2tab = (float*)d_out;

  cvt_all_kernel<<<2048, 256, 0, stream>>>(
      a_log, c2tab, Wd, wdb, Wo, wob, x, xb);

  gemm_bt_kernel<true><<<dim3((MM/128)*(D_MODEL/128)), 512, 0, stream>>>(
      xb, wdb, bd, (void*)deltab, MM, D_MODEL, D_MODEL);

  scan_pass1_kernel<<<dim3(D_MODEL/256, BB*NCH), 256, 0, stream>>>(
      xb, deltab, c2tab, Lc, dts);
  scan_pass2_kernel<<<(BB*D_MODEL*D_STATE)/256, 256, 0, stream>>>(
      c2tab, Lc, dts);
  scan_pass3_kernel<<<dim3(D_MODEL/256, BB*NCH), 256, 0, stream>>>(
      xb, deltab, c2tab, b_param, Lc, yb);

  gemm_bt_kernel<false><<<dim3((MM/128)*(D_MODEL/128)), 512, 0, stream>>>(
      yb, wob, bo, (void*)out, MM, D_MODEL, D_MODEL);
}

// Round 19
// 108.641 us; speedup vs baseline: 1.3281x; 1.2846x over previous
//
#include <hip/hip_runtime.h>
#include <stdint.h>

#define D_MODEL 1024
#define D_STATE 16
#define BB 4
#define TT 2048
#define MM (BB*TT)       /* 8192 rows */
#define NCH 64           /* time chunks */
#define CL (TT/NCH)      /* 32 steps per chunk */

typedef __attribute__((ext_vector_type(4))) float f32x4;
typedef __attribute__((ext_vector_type(8))) short short8;

__device__ __forceinline__ unsigned short f2bf(float f) {
  union { float f; uint32_t u; } v; v.f = f;
  uint32_t r = v.u + 0x7FFFu + ((v.u >> 16) & 1u);   // RNE
  return (unsigned short)(r >> 16);
}
__device__ __forceinline__ float bf2f(unsigned short u) {
  union { uint32_t i; float f; } v; v.i = ((uint32_t)u) << 16; return v.f;
}

__device__ __forceinline__ float softplusf(float v) {
  return v > 20.f ? v : log1pf(expf(v));
}

// fast softplus: ln2 * log2(1 + 2^(v*log2e)) via native v_exp_f32/v_log_f32.
// |err| ~1 ulp of the trans ops; for v<-17 underflows to 0 (true value <4e-8,
// far below bf16 resolution of the delta path). Used in GEMM1 epilogue only.
__device__ __forceinline__ float softplus_fast(float v) {
  if (v > 20.f) return v;
  const float t = __builtin_amdgcn_exp2f(v * 1.44269504088896f);
  return 0.69314718055995f * __builtin_amdgcn_logf(1.0f + t);
}

__device__ __forceinline__ f32x4 splat4(float s) {
  f32x4 r; r[0]=s; r[1]=s; r[2]=s; r[3]=s; return r;
}
__device__ __forceinline__ f32x4 exp2v4(f32x4 v) {
  f32x4 r;
  r[0]=__builtin_amdgcn_exp2f(v[0]);
  r[1]=__builtin_amdgcn_exp2f(v[1]);
  r[2]=__builtin_amdgcn_exp2f(v[2]);
  r[3]=__builtin_amdgcn_exp2f(v[3]);
  return r;
}

// ---- merged prep: c2 table + f32->bf16 of Wd, Wo, x (single launch) --------
#define N4_C ((D_MODEL*D_STATE)/4)       /* 4096  */
#define N4_W ((D_MODEL*D_MODEL)/4)       /* 262144 */
#define N4_X ((MM*D_MODEL)/4)            /* 2097152 */
__global__ __launch_bounds__(256) void cvt_all_kernel(
    const float* __restrict__ a_log, float* __restrict__ c2tab,
    const float* __restrict__ wd_in, unsigned short* __restrict__ wd_out,
    const float* __restrict__ wo_in, unsigned short* __restrict__ wo_out,
    const float* __restrict__ x_in,  unsigned short* __restrict__ x_out)
{
  const int total = N4_C + 2*N4_W + N4_X;
  int i = blockIdx.x * blockDim.x + threadIdx.x;
  const int stride = gridDim.x * blockDim.x;
  for (; i < total; i += stride) {
    if (i < N4_C) {
      float4 v = ((const float4*)a_log)[i];
      float4 o;
      o.x = -(softplusf(v.x) + 1e-4f) * 1.44269504088896f;
      o.y = -(softplusf(v.y) + 1e-4f) * 1.44269504088896f;
      o.z = -(softplusf(v.z) + 1e-4f) * 1.44269504088896f;
      o.w = -(softplusf(v.w) + 1e-4f) * 1.44269504088896f;
      ((float4*)c2tab)[i] = o;
    } else {
      const float4* src; ushort4* dst; int j = i - N4_C;
      if (j < N4_W)        { src = (const float4*)wd_in; dst = (ushort4*)wd_out; }
      else if (j < 2*N4_W) { src = (const float4*)wo_in; dst = (ushort4*)wo_out; j -= N4_W; }
      else                 { src = (const float4*)x_in;  dst = (ushort4*)x_out;  j -= 2*N4_W; }
      float4 v = src[j];
      ushort4 o;
      o.x = f2bf(v.x); o.y = f2bf(v.y); o.z = f2bf(v.z); o.w = f2bf(v.w);
      dst[j] = o;
    }
  }
}

__device__ __forceinline__ void glds16(const char* g, char* l) {
  __builtin_amdgcn_global_load_lds(
      (const __attribute__((address_space(1))) void*)g,
      (__attribute__((address_space(3))) void*)l, 16, 0, 0);
}

// ---------------- bf16 GEMM, B^T layout (R16 kernel, best measured) ---------
// 128x128 tile, BK=64, 512thr/8 waves 2x4 (wave out 64x32), dbuf 64KB LDS,
// contiguous 1KB/wave staging, stage(i+1)-then-vmcnt(4), 2 barriers/iter,
// XCD swizzle, 2 blocks/CU. In-row XOR swizzle: LDS[row][col] holds
// global[row][col ^ ((row&7)<<4)] -> staging coalescing unchanged, reads
// 2-way-free (verified SQ_LDS_BANK_CONFLICT = 0; 52.0-52.7us measured
// R13/R16 — best of 9 structural variants tried R1-R18; matches the
// m102-measured ceiling of this structure class at this shape).
template<bool SOFTPLUS>
__device__ __forceinline__ void stage64(
    const unsigned short* __restrict__ A, const unsigned short* __restrict__ Bm,
    char* Al, char* Bl, int bm, int bn, int k0, int K, int w, int lane)
{
  const int sub  = ((lane & 7) ^ (lane >> 3)) << 4;   // swizzled col of this lane
  #pragma unroll
  for (int r = 0; r < 2; ++r) {
    const int row = r*64 + w*8 + (lane >> 3);         // tile row this lane stages
    const char* ga = (const char*)A  + ((size_t)(bm + row)*K + k0)*2 + sub;
    const char* gb = (const char*)Bm + ((size_t)(bn + row)*K + k0)*2 + sub;
    char* da = Al + r*8192 + w*1024;                  // wave-uniform dest
    char* db = Bl + r*8192 + w*1024;
    glds16(ga, da);
    glds16(gb, db);
  }
}

template<bool SOFTPLUS>   // SOFTPLUS -> softplus epilogue + bf16 output
__global__ __launch_bounds__(512, 4) void gemm_bt_kernel(
    const unsigned short* __restrict__ A,   // M x K bf16 (row-major)
    const unsigned short* __restrict__ Bm,  // N x K bf16 (row-major, i.e. B^T)
    const float* __restrict__ bias,         // N
    void* __restrict__ Cout,                // M x N (bf16 if SOFTPLUS else f32)
    int M, int N, int K)
{
  __shared__ __align__(16) char Al[2][16384];  // [buf][128 rows][128B]
  __shared__ __align__(16) char Bl[2][16384];
  const int tid  = threadIdx.x;
  const int lane = tid & 63;
  const int w    = tid >> 6;           // wave 0..7
  const int wr   = w >> 2, wc = w & 3; // 2x4 wave grid, 64x32 out each
  const int r16  = lane & 15, kh = lane >> 4;

  // T1: bijective XCD chunk swizzle (nwg = 512, % 8 == 0)
  const int nwg   = gridDim.x;
  const int flat  = blockIdx.x;
  const int newid = (flat & 7) * (nwg >> 3) + (flat >> 3);
  const int bm    = (newid >> 3) * 128;
  const int bn    = (newid & 7) * 128;

  // swizzled read columns (per-thread constants)
  const int swz = (r16 & 7) << 4;
  const int c0  = (kh * 16) ^ swz;          // ks = 0
  const int c1  = (64 + kh * 16) ^ swz;     // ks = 1

  f32x4 acc[4][2] = {};
  const int NT = K >> 6;    // 16

  stage64<SOFTPLUS>(A, Bm, Al[0], Bl[0], bm, bn, 0, K, w, lane);

  for (int i = 0; i < NT; ++i) {
    if (i + 1 < NT) {
      stage64<SOFTPLUS>(A, Bm, Al[(i+1)&1], Bl[(i+1)&1], bm, bn, (i+1)*64, K, w, lane);
      asm volatile("s_waitcnt vmcnt(4)" ::: "memory");  // stage i's 4 loads done
    } else {
      asm volatile("s_waitcnt vmcnt(0)" ::: "memory");
    }
    __builtin_amdgcn_s_barrier();   // stage i visible to all waves

    const char* Ab = Al[i & 1] + (wr*64 + r16) * 128;
    const char* Bb = Bl[i & 1] + (wc*32 + r16) * 128;
    short8 af[4][2], bf[2][2];
    #pragma unroll
    for (int m = 0; m < 4; ++m) {
      af[m][0] = *(const short8*)(Ab + m*2048 + c0);
      af[m][1] = *(const short8*)(Ab + m*2048 + c1);
    }
    #pragma unroll
    for (int n = 0; n < 2; ++n) {
      bf[n][0] = *(const short8*)(Bb + n*2048 + c0);
      bf[n][1] = *(const short8*)(Bb + n*2048 + c1);
    }
    #pragma unroll
    for (int ks = 0; ks < 2; ++ks)
      #pragma unroll
      for (int m = 0; m < 4; ++m)
        #pragma unroll
        for (int n = 0; n < 2; ++n)
          acc[m][n] = __builtin_amdgcn_mfma_f32_16x16x32_bf16(af[m][ks], bf[n][ks], acc[m][n], 0, 0, 0);

    __builtin_amdgcn_s_barrier();   // reads of buf[i&1] retired before overwrite
  }

  // epilogue: row = bm + wr*64 + m*16 + kh*4 + j ; col = bn + wc*32 + n*16 + r16
  #pragma unroll
  for (int n = 0; n < 2; ++n) {
    const int col = bn + wc*32 + n*16 + r16;
    const float bv = bias[col];
    #pragma unroll
    for (int m = 0; m < 4; ++m) {
      #pragma unroll
      for (int j = 0; j < 4; ++j) {
        const int row = bm + wr*64 + m*16 + kh*4 + j;
        float v = acc[m][n][j] + bv;
        if (SOFTPLUS) {
          v = softplus_fast(v);
          ((unsigned short*)Cout)[(size_t)row*N + col] = f2bf(v);
        } else {
          ((float*)Cout)[(size_t)row*N + col] = v;
        }
      }
    }
  }
}

// ---------------- scan pass 1: per-chunk local state L and sum(dt) ----------
__global__ __launch_bounds__(256) void scan_pass1_kernel(
    const unsigned short* __restrict__ x, const unsigned short* __restrict__ delta,
    const float* __restrict__ c2tab,
    float* __restrict__ Lc, float* __restrict__ dts_out)
{
  const int e  = blockIdx.x * 256 + threadIdx.x;
  const int b  = blockIdx.y >> 6;            // NCH = 64
  const int c  = blockIdx.y & (NCH-1);

  const f32x4* c2p = (const f32x4*)(c2tab + (size_t)e*D_STATE);
  const f32x4 c20=c2p[0], c21=c2p[1], c22=c2p[2], c23=c2p[3];

  f32x4 S0=splat4(0.f), S1=splat4(0.f), S2=splat4(0.f), S3=splat4(0.f);
  const size_t base = ((size_t)b*TT + (size_t)c*CL)*D_MODEL + e;
  const unsigned short* xp = x + base;
  const unsigned short* dp = delta + base;
  float dts = 0.f;
  #pragma unroll 4
  for (int t = 0; t < CL; ++t) {
    const float dt = bf2f(dp[(size_t)t*D_MODEL]);
    const float xv = bf2f(xp[(size_t)t*D_MODEL]);
    dts += dt;
    const f32x4 u4 = splat4(dt*xv);
    const f32x4 d4 = splat4(dt);
    S0 = exp2v4(c20*d4)*S0 + u4;
    S1 = exp2v4(c21*d4)*S1 + u4;
    S2 = exp2v4(c22*d4)*S2 + u4;
    S3 = exp2v4(c23*d4)*S3 + u4;
  }
  const size_t ci = ((size_t)c*BB + b)*D_MODEL + e;
  dts_out[ci] = dts;
  f32x4* Lp = (f32x4*)&Lc[ci*D_STATE];
  Lp[0]=S0; Lp[1]=S1; Lp[2]=S2; Lp[3]=S3;
}

// ---------------- scan pass 2: in-place exclusive scan over chunks ----------
__global__ __launch_bounds__(256) void scan_pass2_kernel(
    const float* __restrict__ c2tab,
    float* __restrict__ Lc, const float* __restrict__ dts)
{
  const int tid = blockIdx.x * 256 + threadIdx.x;  // < 65536
  const int e = (tid >> 4) & (D_MODEL - 1);
  const int b = tid >> 14;
  const float c2 = c2tab[tid & (D_MODEL*D_STATE - 1)];  // e*16 + s
  float S = 0.f;
  for (int c = 0; c < NCH; ++c) {
    const size_t ce  = ((size_t)c*BB + b)*D_MODEL + e;
    const size_t idx = ce*D_STATE + (tid & 15);
    const float L  = Lc[idx];
    const float Ac = __builtin_amdgcn_exp2f(c2 * dts[ce]);
    Lc[idx] = S;                 // exclusive prefix (chunk initial state)
    S = Ac*S + L;
  }
}

// ---------------- scan pass 3: recompute with carry-in, emit y (bf16) -------
__global__ __launch_bounds__(256) void scan_pass3_kernel(
    const unsigned short* __restrict__ x, const unsigned short* __restrict__ delta,
    const float* __restrict__ c2tab, const float* __restrict__ b_param,
    const float* __restrict__ Lc, unsigned short* __restrict__ yb)
{
  const int e  = blockIdx.x * 256 + threadIdx.x;
  const int b  = blockIdx.y >> 6;
  const int c  = blockIdx.y & (NCH-1);

  const f32x4* c2p = (const f32x4*)(c2tab + (size_t)e*D_STATE);
  const f32x4 c20=c2p[0], c21=c2p[1], c22=c2p[2], c23=c2p[3];
  const f32x4* bpp = (const f32x4*)(b_param + (size_t)e*D_STATE);
  const f32x4 bp0=bpp[0], bp1=bpp[1], bp2=bpp[2], bp3=bpp[3];

  const size_t ci = ((size_t)c*BB + b)*D_MODEL + e;
  const f32x4* Lp = (const f32x4*)&Lc[ci*D_STATE];
  f32x4 S0=Lp[0], S1=Lp[1], S2=Lp[2], S3=Lp[3];

  const size_t base = ((size_t)b*TT + (size_t)c*CL)*D_MODEL + e;
  const unsigned short* xp = x + base;
  const unsigned short* dp = delta + base;
  #pragma unroll 4
  for (int t = 0; t < CL; ++t) {
    const float dt = bf2f(dp[(size_t)t*D_MODEL]);
    const float xv = bf2f(xp[(size_t)t*D_MODEL]);
    const f32x4 u4 = splat4(dt*xv);
    const f32x4 d4 = splat4(dt);
    S0 = exp2v4(c20*d4)*S0 + u4;
    S1 = exp2v4(c21*d4)*S1 + u4;
    S2 = exp2v4(c22*d4)*S2 + u4;
    S3 = exp2v4(c23*d4)*S3 + u4;
    const f32x4 yv = bp0*S0 + bp1*S1 + bp2*S2 + bp3*S3;
    const float y = (yv[0]+yv[1]) + (yv[2]+yv[3]);
    yb[base + (size_t)t*D_MODEL] = f2bf(y);
  }
}

// ---------------------------------------------------------------------------
extern "C" void kernel_launch(void* const* d_in, const int* in_sizes, int n_in,
                              void* d_out, int out_size, void* d_ws, size_t ws_size,
                              hipStream_t stream)
{
  (void)in_sizes; (void)n_in; (void)out_size; (void)ws_size;
  const float* x       = (const float*)d_in[0];
  const float* Wd      = (const float*)d_in[1];
  const float* bd      = (const float*)d_in[2];
  const float* a_log   = (const float*)d_in[3];
  const float* b_param = (const float*)d_in[4];
  const float* Wo      = (const float*)d_in[5];
  const float* bo      = (const float*)d_in[6];
  float* out = (float*)d_out;

  // workspace layout, 1MB units, no overlaps:
  //   xb[0,16M) wdb[16M,18M) wob[18M,20M) deltab[20M,36M) yb[36M,52M)
  //   Lc[52M,68M) dts[68M,69M)
  char* ws = (char*)d_ws;
  unsigned short* xb     = (unsigned short*)(ws);
  unsigned short* wdb    = (unsigned short*)(ws + 16777216);
  unsigned short* wob    = (unsigned short*)(ws + 18874368);
  unsigned short* deltab = (unsigned short*)(ws + 20971520);
  unsigned short* yb     = (unsigned short*)(ws + 37748736);
  float*          Lc     = (float*)(ws + 54525952);
  float*          dts    = (float*)(ws + 71303168);

  // c2 table (64 KB) at the head of d_out; consumed by scans, then GEMM2
  // overwrites all of d_out. Deterministic each call.
  float* c2tab = (float*)d_out;

  cvt_all_kernel<<<2048, 256, 0, stream>>>(
      a_log, c2tab, Wd, wdb, Wo, wob, x, xb);

  gemm_bt_kernel<true><<<dim3((MM/128)*(D_MODEL/128)), 512, 0, stream>>>(
      xb, wdb, bd, (void*)deltab, MM, D_MODEL, D_MODEL);

  scan_pass1_kernel<<<dim3(D_MODEL/256, BB*NCH), 256, 0, stream>>>(
      xb, deltab, c2tab, Lc, dts);
  scan_pass2_kernel<<<(BB*D_MODEL*D_STATE)/256, 256, 0, stream>>>(
      c2tab, Lc, dts);
  scan_pass3_kernel<<<dim3(D_MODEL/256, BB*NCH), 256, 0, stream>>>(
      xb, deltab, c2tab, b_param, Lc, yb);

  gemm_bt_kernel<false><<<dim3((MM/128)*(D_MODEL/128)), 512, 0, stream>>>(
      yb, wob, bo, (void*)out, MM, D_MODEL, D_MODEL);
}